// Round 13
// baseline (576.482 us; speedup 1.0000x reference)
//
#include <hip/hip_runtime.h>
#include <hip/hip_bf16.h>
#include <stdint.h>

#define NTOK 8192
#define DEMB 1024
#define HDIM 4096
#define NEXP 8
#define LINF 1824
#define MAXPAD 18432  // max sum of per-expert 256-padded counts

typedef __attribute__((ext_vector_type(8))) __bf16 bf16x8;
typedef __attribute__((ext_vector_type(4))) __bf16 bf16x4v;
typedef __attribute__((ext_vector_type(4))) float f32x4;

__device__ __forceinline__ void gload_lds16(const void* g, void* l) {
  __builtin_amdgcn_global_load_lds(
      (const __attribute__((address_space(1))) void*)g,
      (__attribute__((address_space(3))) void*)l, 16, 0, 0);
}

__device__ __forceinline__ float dot4(float4 a, float4 b) {
  return a.x*b.x + a.y*b.y + a.z*b.z + a.w*b.w;
}

// ---------------- logits + softmax + top2 (+ fused x->bf16 convert) ---------
__global__ void __launch_bounds__(256) k_logits(
    const float* __restrict__ x, const float* __restrict__ dt,
    const float* __restrict__ dd, const float* __restrict__ drg,
    const float* __restrict__ de, const float* __restrict__ city,
    const float* __restrict__ Wg, const float* __restrict__ bg,
    const int* __restrict__ city_index,
    float* __restrict__ gate1, int* __restrict__ top_i, float2* __restrict__ top_g,
    __bf16* __restrict__ xb)
{
  __shared__ float WgT[NEXP * LINF];   // [e][f]
  const int tid = threadIdx.x;
  const float4* Wg4 = (const float4*)Wg;
  for (int i = tid; i < LINF * NEXP / 4; i += 256) {
    float4 v = Wg4[i];
    int e0 = (i & 1) * 4, f = i >> 1;
    WgT[(e0+0)*LINF + f] = v.x; WgT[(e0+1)*LINF + f] = v.y;
    WgT[(e0+2)*LINF + f] = v.z; WgT[(e0+3)*LINF + f] = v.w;
  }
  __syncthreads();

  const int wave = tid >> 6, lane = tid & 63;
  const int ci = city_index[0];
  const float4* city4 = (const float4*)(city + ci*32);
  const float4 z4 = {0.f, 0.f, 0.f, 0.f};

  #pragma unroll
  for (int k = 0; k < 4; ++k) {
    const int t = blockIdx.x*16 + wave*4 + k;
    const float4* x4 = (const float4*)x + (size_t)t*256;
    float4 xv0 = x4[lane], xv1 = x4[64+lane], xv2 = x4[128+lane], xv3 = x4[192+lane];

    {
      bf16x4v* xrow = (bf16x4v*)(xb + (size_t)t*1024);
      bf16x4v o0, o1, o2, o3;
      o0[0]=(__bf16)xv0.x; o0[1]=(__bf16)xv0.y; o0[2]=(__bf16)xv0.z; o0[3]=(__bf16)xv0.w;
      o1[0]=(__bf16)xv1.x; o1[1]=(__bf16)xv1.y; o1[2]=(__bf16)xv1.z; o1[3]=(__bf16)xv1.w;
      o2[0]=(__bf16)xv2.x; o2[1]=(__bf16)xv2.y; o2[2]=(__bf16)xv2.z; o2[3]=(__bf16)xv2.w;
      o3[0]=(__bf16)xv3.x; o3[1]=(__bf16)xv3.y; o3[2]=(__bf16)xv3.z; o3[3]=(__bf16)xv3.w;
      xrow[lane] = o0; xrow[64+lane] = o1; xrow[128+lane] = o2; xrow[192+lane] = o3;
    }

    float4 cv = (lane < 8) ? city4[lane] : z4;
    float4 tv = ((const float4*)dt)[(size_t)t*64 + lane];
    float4 dv = ((const float4*)dd)[(size_t)t*64 + lane];
    float4 rv = z4, ev = z4;
    if (lane < 32) {
      rv = ((const float4*)drg)[(size_t)t*32 + lane];
      ev = ((const float4*)de )[(size_t)t*32 + lane];
    }
    float a[8];
    const int l8 = lane & 7, l32 = lane & 31;
    #pragma unroll
    for (int e = 0; e < 8; ++e) {
      const float4* W = (const float4*)(WgT + e*LINF);
      float s = dot4(xv0, W[lane]) + dot4(xv1, W[64+lane])
              + dot4(xv2, W[128+lane]) + dot4(xv3, W[192+lane]);
      s += dot4(cv, W[256 + l8]);
      s += dot4(tv, W[264 + lane]) + dot4(dv, W[328 + lane]);
      s += dot4(rv, W[392 + l32]) + dot4(ev, W[424 + l32]);
      a[e] = s;
    }
    #pragma unroll
    for (int off = 32; off > 0; off >>= 1)
      #pragma unroll
      for (int e = 0; e < 8; ++e) a[e] += __shfl_xor(a[e], off);

    float lg[8];
    #pragma unroll
    for (int e = 0; e < 8; ++e) lg[e] = a[e] + bg[e];
    float mx = lg[0];
    #pragma unroll
    for (int e = 1; e < 8; ++e) mx = fmaxf(mx, lg[e]);
    float ex[8]; float s = 0.f;
    #pragma unroll
    for (int e = 0; e < 8; ++e) { ex[e] = expf(lg[e] - mx); s += ex[e]; }
    int i1 = 0; float l1 = lg[0];
    #pragma unroll
    for (int e = 1; e < 8; ++e) if (lg[e] > l1) { l1 = lg[e]; i1 = e; }
    int i2 = -1; float l2 = -1e30f;
    #pragma unroll
    for (int e = 0; e < 8; ++e) if (e != i1 && lg[e] > l2) { l2 = lg[e]; i2 = e; }
    float e2 = expf(l2 - l1);

    if (lane == 0) {
      float inv = 1.f / s;
      float4 o0 = { ex[0]*inv, ex[1]*inv, ex[2]*inv, ex[3]*inv };
      float4 o1 = { ex[4]*inv, ex[5]*inv, ex[6]*inv, ex[7]*inv };
      float4* gp = (float4*)(gate1 + (size_t)t*8);
      gp[0] = o0; gp[1] = o1;
      top_i[t] = i1 | (i2 << 4);
      float2 g = { 1.f / (1.f + e2), e2 / (1.f + e2) };
      top_g[t] = g;
    }
  }
}

// ---------------- build expert lists: block-aggregated atomics ----------------
__global__ void __launch_bounds__(256) k_build(
    const int* __restrict__ top_i, const float2* __restrict__ top_g,
    int* __restrict__ counts, int* __restrict__ ex_tok, float* __restrict__ ex_gate,
    int2* __restrict__ ppos)
{
  __shared__ int lcnt[8], lbase[8];
  const int tid = threadIdx.x;
  if (tid < 8) lcnt[tid] = 0;
  __syncthreads();
  const int t = blockIdx.x*256 + tid;
  const int ti = top_i[t];
  const int i1 = ti & 15, i2 = ti >> 4;
  const float2 g = top_g[t];
  int p1 = atomicAdd(&lcnt[i1], 1);
  int p2 = atomicAdd(&lcnt[i2], 1);
  __syncthreads();
  if (tid < 8) lbase[tid] = atomicAdd(&counts[tid], lcnt[tid]);
  __syncthreads();
  int s1 = lbase[i1] + p1; ex_tok[i1*NTOK+s1] = t; ex_gate[i1*NTOK+s1] = g.x;
  int s2 = lbase[i2] + p2; ex_tok[i2*NTOK+s2] = t; ex_gate[i2*NTOK+s2] = g.y;
  int2 pp = { i1 | (s1 << 3), i2 | (s2 << 3) };
  ppos[t] = pp;
}

__global__ void k_finalize(const int* __restrict__ counts, int* __restrict__ seg) {
  if (threadIdx.x == 0 && blockIdx.x == 0) {
    int s = 0;
    for (int e = 0; e < 8; ++e) { seg[e] = s; s += (counts[e] + 255) & ~255; }
    seg[8] = s;
  }
}

// W [E][R][C] f32 -> WT [E][C][R] bf16 — vectorized (float4 in, bf16x8 out)
template<int RDIM, int CDIM>
__global__ void __launch_bounds__(256) k_tconv(
    const float* __restrict__ W, __bf16* __restrict__ WT)
{
  const int e  = blockIdx.z;
  const int c0 = blockIdx.x * 64, r0 = blockIdx.y * 64;
  __shared__ float tb[64 * 65];          // [srccol][srcrow], pad 65
  const float* src = W  + (size_t)e * RDIM * CDIM + (size_t)r0 * CDIM + c0;
  __bf16*      dst = WT + (size_t)e * RDIM * CDIM + (size_t)c0 * RDIM + r0;
  const int tx = threadIdx.x & 15, ty = threadIdx.x >> 4;   // 16x16
  #pragma unroll
  for (int i = 0; i < 4; ++i) {
    int r = ty + i*16;
    float4 v = *(const float4*)(src + (size_t)r*CDIM + tx*4);
    tb[(tx*4+0)*65 + r] = v.x; tb[(tx*4+1)*65 + r] = v.y;
    tb[(tx*4+2)*65 + r] = v.z; tb[(tx*4+3)*65 + r] = v.w;
  }
  __syncthreads();
  const int sg = threadIdx.x & 7, dr8 = threadIdx.x >> 3;  // 32 dst rows/iter
  #pragma unroll
  for (int i = 0; i < 2; ++i) {
    int d = dr8 + i*32;
    const float* row = tb + d*65 + sg*8;
    bf16x8 o;
    #pragma unroll
    for (int j = 0; j < 8; ++j) o[j] = (__bf16)row[j];
    *(bf16x8*)(dst + (size_t)d*RDIM + sg*8) = o;
  }
}

// ====== grouped GEMM: 128x128 tile, BK=32, dbuf 32KB => 4-5 blocks/CU =======
// Per-wave 64x64 (4Mx4N frags of 16x16x32, one MFMA each per K-tile).
// LDS per buf 16KB: A [128r][32k] @0, B [128c][32k] @8K; rows are 64B =
// 4x16B slots, swizzle slot ^= (row>>1)&3 (2-way granule alias = free).
// Loop: {ISSUE t+1 (4 gloads) -> 8 ds_read -> 16 MFMA -> vmcnt(0)+barrier}.
// Latency hidden by TLP: 4-5 independent barrier domains per CU (m97/m114).
template<int KDIM, int KFULL, int NDIM, bool G1>
__global__ void __launch_bounds__(256, 4) k_moe_gemm(
    const __bf16* __restrict__ Abase, const __bf16* __restrict__ WT,
    const float* __restrict__ bias,
    const int* __restrict__ seg, const int* __restrict__ counts,
    const int* __restrict__ ex_tok,
    int chunk0, __bf16* __restrict__ dstbuf)
{
  constexpr int NT = KDIM / 32;
  const int nx = gridDim.x, ny = gridDim.y, nz = gridDim.z;
  const int total = nx * ny * nz;
  int flat;
  if (G1) flat = blockIdx.x + nx * blockIdx.y;                       // bx fastest
  else    flat = blockIdx.y + ny * (blockIdx.x + nx * blockIdx.z);   // by fastest
  { int q = total >> 3, r = total & 7; int xcd = flat & 7, idx = flat >> 3;
    flat = (xcd < r ? xcd*(q+1) : r*(q+1) + (xcd-r)*q) + idx; }
  int bx, by, bz;
  if (G1) { bx = flat % nx; by = flat / nx; bz = 0; }
  else    { by = flat % ny; int f2 = flat / ny; bx = f2 % nx; bz = f2 / nx; }

  const int segtot = seg[8];
  const int row0 = chunk0 + bx * 128;
  if (row0 >= segtot) return;
  int e = 0;
  #pragma unroll
  for (int qq = 1; qq < 8; ++qq) if (row0 >= seg[qq]) e = qq;
  const int cnt = counts[e], sege = seg[e];
  const int n0 = by * 128;
  const int kbase = bz * KDIM;

  __shared__ __align__(16) char smem[32768];   // 2 x 16KB dbuf; C-stage 32KB

  const int tid = threadIdx.x;
  const int wid = tid >> 6, lane = tid & 63;
  const int wm = wid >> 1, wn = wid & 1;        // 2M x 2N waves
  const int l15 = lane & 15, l4 = lane >> 4;
  const __bf16* Bsrc = WT + (size_t)e * NDIM * KFULL;

  float bv[4];
  if (G1) {
    #pragma unroll
    for (int N = 0; N < 4; ++N)
      bv[N] = bias[(size_t)e*NDIM + n0 + wn*64 + N*16 + l15];
    asm volatile("" :: "v"(bv[0]), "v"(bv[1]), "v"(bv[2]), "v"(bv[3]));
  }

  // staging: A half = 512 chunks of 16B (row = g>>2), B half same.
  // source k-chunk kb = (g&3) ^ ((g>>3)&3)  [slot ^ (row>>1)&3, involution]
  const __bf16* spA[2]; const __bf16* spB[2];
  #pragma unroll
  for (int j = 0; j < 2; ++j) {
    int g = j*256 + tid;
    int sl = g >> 2;                       // row 0..127
    int kb = (g & 3) ^ ((g >> 3) & 3);     // swizzled source k-chunk (0..3)
    int arow;
    if (G1) { int lr = row0 + sl - sege; arow = (lr < cnt) ? ex_tok[e*NTOK + lr] : 0; }
    else    { arow = row0 + sl - chunk0; }
    spA[j] = Abase + (size_t)arow * KFULL + kbase + kb*8;
    spB[j] = Bsrc  + (size_t)(n0 + sl) * KFULL + kbase + kb*8;
  }

  // read offsets: row r, k-chunk c at LDS slot c ^ ((r>>1)&3)
  const int xo = (l4 ^ ((l15 >> 1) & 3)) * 16;
  int arb[4], brb[4];
  #pragma unroll
  for (int m = 0; m < 4; ++m) arb[m] = (wm*64 + m*16 + l15) * 64 + xo;
  #pragma unroll
  for (int n = 0; n < 4; ++n) brb[n] = 8192 + (wn*64 + n*16 + l15) * 64 + xo;

  auto ISSUE = [&](int tt) {
    char* b = smem + (tt & 1) * 16384;
    #pragma unroll
    for (int j = 0; j < 2; ++j) {
      gload_lds16(spA[j] + tt*32, b + (j*256 + tid)*16);
      gload_lds16(spB[j] + tt*32, b + 8192 + (j*256 + tid)*16);
    }
  };

  f32x4 acc[4][4] = {};

  // prologue: stage tile 0, drain, barrier
  ISSUE(0);
  asm volatile("s_waitcnt vmcnt(0)" ::: "memory");
  __builtin_amdgcn_s_barrier();

  for (int t = 0; t < NT; ++t) {
    const char* cb = smem + (t & 1) * 16384;
    if (t + 1 < NT) ISSUE(t + 1);
    bf16x8 af[4], bfv[4];
    #pragma unroll
    for (int m = 0; m < 4; ++m) af[m]  = *(const bf16x8*)(cb + arb[m]);
    #pragma unroll
    for (int n = 0; n < 4; ++n) bfv[n] = *(const bf16x8*)(cb + brb[n]);
    __builtin_amdgcn_s_setprio(1);
    #pragma unroll
    for (int m = 0; m < 4; ++m)
      #pragma unroll
      for (int n = 0; n < 4; ++n)
        acc[m][n] = __builtin_amdgcn_mfma_f32_16x16x32_bf16(af[m], bfv[n], acc[m][n], 0, 0, 0);
    __builtin_amdgcn_s_setprio(0);
    // all reads consumed by MFMAs (compiler lgkm waits) before the barrier;
    // vmcnt(0) drains t+1's stage, covered by this tile's reads+compute and
    // by the other 3-4 resident blocks' work.
    asm volatile("s_waitcnt vmcnt(0)" ::: "memory");
    __builtin_amdgcn_s_barrier();
  }

  // ---- epilogue: bias (+GELU if G1), stage 128x128 bf16 C in LDS, store
  __bf16* Cl = (__bf16*)smem;   // 32 KB
  #pragma unroll
  for (int M = 0; M < 4; ++M) {
    #pragma unroll
    for (int N = 0; N < 4; ++N) {
      #pragma unroll
      for (int r2 = 0; r2 < 4; ++r2) {
        float v = acc[M][N][r2];
        if (G1) {
          v += bv[N];
          float z = 2.302208f * (v + 0.044715f * v * v * v);  // 2u*log2(e)
          v = v / (1.f + exp2f(-z));
        }
        Cl[(wm*64 + M*16 + l4*4 + r2)*128 + wn*64 + N*16 + l15] = (__bf16)v;
      }
    }
  }
  __syncthreads();
  const int drow0 = G1 ? (row0 - chunk0) : row0;
  __bf16* dst = dstbuf + (G1 ? (size_t)0 : (size_t)bz * MAXPAD * NDIM);
  #pragma unroll
  for (int it = 0; it < 8; ++it) {
    int idx2 = it*256 + tid;
    int rr = idx2 >> 4, c8 = (idx2 & 15) * 8;
    *(bf16x8*)(dst + (size_t)(drow0 + rr)*NDIM + n0 + c8) =
        *(const bf16x8*)(Cl + rr*128 + c8);
  }
}

// -------- combine: out[t] = g1*(ΣP+b2)[pos1] + g2*(ΣP+b2)[pos2] (splitK=2) ---
__global__ void __launch_bounds__(256) k_combine(
    const __bf16* __restrict__ pbuf, const int2* __restrict__ ppos,
    const float2* __restrict__ top_g, const int* __restrict__ seg,
    const float* __restrict__ b2, float* __restrict__ out)
{
  const int t = blockIdx.x, tid = threadIdx.x;
  const int2 pp = ppos[t];
  const float2 g = top_g[t];
  const int e1 = pp.x & 7, i1 = pp.x >> 3;
  const int e2 = pp.y & 7, i2 = pp.y >> 3;
  const size_t r1 = (size_t)(seg[e1] + i1) * DEMB;
  const size_t r2 = (size_t)(seg[e2] + i2) * DEMB;
  const int c = tid * 4;
  float4 ba = *(const float4*)(b2 + (size_t)e1*DEMB + c);
  float4 bb = *(const float4*)(b2 + (size_t)e2*DEMB + c);
  float s1x = ba.x, s1y = ba.y, s1z = ba.z, s1w = ba.w;
  float s2x = bb.x, s2y = bb.y, s2z = bb.z, s2w = bb.w;
  #pragma unroll
  for (int p = 0; p < 2; ++p) {
    const __bf16* pb = pbuf + (size_t)p * MAXPAD * DEMB;
    bf16x4v a = *(const bf16x4v*)(pb + r1 + c);
    bf16x4v b = *(const bf16x4v*)(pb + r2 + c);
    s1x += (float)a[0]; s1y += (float)a[1]; s1z += (float)a[2]; s1w += (float)a[3];
    s2x += (float)b[0]; s2y += (float)b[1]; s2z += (float)b[2]; s2w += (float)b[3];
  }
  float4 o;
  o.x = g.x*s1x + g.y*s2x;
  o.y = g.x*s1y + g.y*s2y;
  o.z = g.x*s1z + g.y*s2z;
  o.w = g.x*s1w + g.y*s2w;
  *(float4*)(out + (size_t)t*DEMB + c) = o;
}

// ---------------- host ----------------
extern "C" void kernel_launch(void* const* d_in, const int* in_sizes, int n_in,
                              void* d_out, int out_size, void* d_ws, size_t ws_size,
                              hipStream_t stream)
{
  const float* x   = (const float*)d_in[0];
  const float* dt  = (const float*)d_in[1];
  const float* dd  = (const float*)d_in[2];
  const float* drg = (const float*)d_in[3];
  const float* de  = (const float*)d_in[4];
  const float* city= (const float*)d_in[5];
  const float* Wg  = (const float*)d_in[6];
  const float* bg  = (const float*)d_in[7];
  const float* W1  = (const float*)d_in[8];
  const float* b1  = (const float*)d_in[9];
  const float* W2  = (const float*)d_in[10];
  const float* b2  = (const float*)d_in[11];
  const int* city_index = (const int*)d_in[12];

  float* out   = (float*)d_out;                    // [NTOK][1024]
  float* gate1 = out + (size_t)NTOK * DEMB;        // [NTOK][8]

  char* p = (char*)d_ws;
  int*    counts  = (int*)p;      p += 256;
  int*    seg     = (int*)p;      p += 256;
  int*    top_i   = (int*)p;      p += (size_t)NTOK*4;
  float2* top_g   = (float2*)p;   p += (size_t)NTOK*8;
  int2*   ppos    = (int2*)p;     p += (size_t)NTOK*8;
  int*    ex_tok  = (int*)p;      p += (size_t)NTOK*NEXP*4;
  float*  ex_gate = (float*)p;    p += (size_t)NTOK*NEXP*4;
  __bf16* xb      = (__bf16*)p;   p += (size_t)NTOK*DEMB*2;
  __bf16* W1T     = (__bf16*)p;   p += (size_t)NEXP*DEMB*HDIM*2;
  __bf16* W2T     = (__bf16*)p;   p += (size_t)NEXP*DEMB*HDIM*2;
  __bf16* pbuf    = (__bf16*)p;   p += (size_t)2*MAXPAD*DEMB*2;   // split-K=2
  __bf16* hbuf    = (__bf16*)p;

  size_t fixed = (size_t)(p - (char*)d_ws);
  int CH = MAXPAD;  // single chunk if workspace allows
  while (CH > 0 && fixed + (size_t)CH * HDIM * 2 > ws_size) CH -= 256;
  if (CH <= 0) return;
  int nch = (MAXPAD + CH - 1) / CH;

  (void)hipMemsetAsync(counts, 0, 64, stream);

  k_tconv<DEMB, HDIM><<<dim3(HDIM/64, DEMB/64, NEXP), 256, 0, stream>>>(W1, W1T);
  k_tconv<HDIM, DEMB><<<dim3(DEMB/64, HDIM/64, NEXP), 256, 0, stream>>>(W2, W2T);

  k_logits<<<NTOK/16, 256, 0, stream>>>(x, dt, dd, drg, de, city, Wg, bg,
                                        city_index, gate1, top_i, top_g, xb);
  k_build<<<NTOK/256, 256, 0, stream>>>(top_i, top_g, counts, ex_tok, ex_gate, ppos);
  k_finalize<<<1, 64, 0, stream>>>(counts, seg);

  for (int c = 0; c < nch; ++c) {
    k_moe_gemm<1024, 1024, HDIM, true><<<dim3(CH/128, HDIM/128, 1), 256, 0, stream>>>(
        xb, W1T, b1, seg, counts, ex_tok, c*CH, hbuf);
    k_moe_gemm<2048, 4096, DEMB, false><<<dim3(CH/128, DEMB/128, 2), 256, 0, stream>>>(
        hbuf, W2T, b2, seg, counts, ex_tok, c*CH, pbuf);
  }
  k_combine<<<NTOK, 256, 0, stream>>>(pbuf, ppos, top_g, seg, b2, out);
}

// Round 14
// 518.616 us; speedup vs baseline: 1.1116x; 1.1116x over previous
//
#include <hip/hip_runtime.h>
#include <hip/hip_bf16.h>
#include <stdint.h>

#define NTOK 8192
#define DEMB 1024
#define HDIM 4096
#define NEXP 8
#define LINF 1824
#define MAXPAD 18432  // max sum of per-expert 256-padded counts

typedef __attribute__((ext_vector_type(8))) __bf16 bf16x8;
typedef __attribute__((ext_vector_type(4))) __bf16 bf16x4v;
typedef __attribute__((ext_vector_type(4))) float f32x4;

__device__ __forceinline__ void gload_lds16(const void* g, void* l) {
  __builtin_amdgcn_global_load_lds(
      (const __attribute__((address_space(1))) void*)g,
      (__attribute__((address_space(3))) void*)l, 16, 0, 0);
}

__device__ __forceinline__ float dot4(float4 a, float4 b) {
  return a.x*b.x + a.y*b.y + a.z*b.z + a.w*b.w;
}

// ---------------- logits + softmax + top2 (+ fused x->bf16 convert) ---------
__global__ void __launch_bounds__(256) k_logits(
    const float* __restrict__ x, const float* __restrict__ dt,
    const float* __restrict__ dd, const float* __restrict__ drg,
    const float* __restrict__ de, const float* __restrict__ city,
    const float* __restrict__ Wg, const float* __restrict__ bg,
    const int* __restrict__ city_index,
    float* __restrict__ gate1, int* __restrict__ top_i, float2* __restrict__ top_g,
    __bf16* __restrict__ xb)
{
  __shared__ float WgT[NEXP * LINF];   // [e][f]
  const int tid = threadIdx.x;
  const float4* Wg4 = (const float4*)Wg;
  for (int i = tid; i < LINF * NEXP / 4; i += 256) {
    float4 v = Wg4[i];
    int e0 = (i & 1) * 4, f = i >> 1;
    WgT[(e0+0)*LINF + f] = v.x; WgT[(e0+1)*LINF + f] = v.y;
    WgT[(e0+2)*LINF + f] = v.z; WgT[(e0+3)*LINF + f] = v.w;
  }
  __syncthreads();

  const int wave = tid >> 6, lane = tid & 63;
  const int ci = city_index[0];
  const float4* city4 = (const float4*)(city + ci*32);
  const float4 z4 = {0.f, 0.f, 0.f, 0.f};

  #pragma unroll
  for (int k = 0; k < 4; ++k) {
    const int t = blockIdx.x*16 + wave*4 + k;
    const float4* x4 = (const float4*)x + (size_t)t*256;
    float4 xv0 = x4[lane], xv1 = x4[64+lane], xv2 = x4[128+lane], xv3 = x4[192+lane];

    // fused convert: write xb row t as bf16
    {
      bf16x4v* xrow = (bf16x4v*)(xb + (size_t)t*1024);
      bf16x4v o0, o1, o2, o3;
      o0[0]=(__bf16)xv0.x; o0[1]=(__bf16)xv0.y; o0[2]=(__bf16)xv0.z; o0[3]=(__bf16)xv0.w;
      o1[0]=(__bf16)xv1.x; o1[1]=(__bf16)xv1.y; o1[2]=(__bf16)xv1.z; o1[3]=(__bf16)xv1.w;
      o2[0]=(__bf16)xv2.x; o2[1]=(__bf16)xv2.y; o2[2]=(__bf16)xv2.z; o2[3]=(__bf16)xv2.w;
      o3[0]=(__bf16)xv3.x; o3[1]=(__bf16)xv3.y; o3[2]=(__bf16)xv3.z; o3[3]=(__bf16)xv3.w;
      xrow[lane] = o0; xrow[64+lane] = o1; xrow[128+lane] = o2; xrow[192+lane] = o3;
    }

    float4 cv = (lane < 8) ? city4[lane] : z4;
    float4 tv = ((const float4*)dt)[(size_t)t*64 + lane];
    float4 dv = ((const float4*)dd)[(size_t)t*64 + lane];
    float4 rv = z4, ev = z4;
    if (lane < 32) {
      rv = ((const float4*)drg)[(size_t)t*32 + lane];
      ev = ((const float4*)de )[(size_t)t*32 + lane];
    }
    float a[8];
    const int l8 = lane & 7, l32 = lane & 31;
    #pragma unroll
    for (int e = 0; e < 8; ++e) {
      const float4* W = (const float4*)(WgT + e*LINF);
      float s = dot4(xv0, W[lane]) + dot4(xv1, W[64+lane])
              + dot4(xv2, W[128+lane]) + dot4(xv3, W[192+lane]);
      s += dot4(cv, W[256 + l8]);
      s += dot4(tv, W[264 + lane]) + dot4(dv, W[328 + lane]);
      s += dot4(rv, W[392 + l32]) + dot4(ev, W[424 + l32]);
      a[e] = s;
    }
    #pragma unroll
    for (int off = 32; off > 0; off >>= 1)
      #pragma unroll
      for (int e = 0; e < 8; ++e) a[e] += __shfl_xor(a[e], off);

    float lg[8];
    #pragma unroll
    for (int e = 0; e < 8; ++e) lg[e] = a[e] + bg[e];
    float mx = lg[0];
    #pragma unroll
    for (int e = 1; e < 8; ++e) mx = fmaxf(mx, lg[e]);
    float ex[8]; float s = 0.f;
    #pragma unroll
    for (int e = 0; e < 8; ++e) { ex[e] = expf(lg[e] - mx); s += ex[e]; }
    int i1 = 0; float l1 = lg[0];
    #pragma unroll
    for (int e = 1; e < 8; ++e) if (lg[e] > l1) { l1 = lg[e]; i1 = e; }
    int i2 = -1; float l2 = -1e30f;
    #pragma unroll
    for (int e = 0; e < 8; ++e) if (e != i1 && lg[e] > l2) { l2 = lg[e]; i2 = e; }
    float e2 = expf(l2 - l1);

    if (lane == 0) {
      float inv = 1.f / s;
      float4 o0 = { ex[0]*inv, ex[1]*inv, ex[2]*inv, ex[3]*inv };
      float4 o1 = { ex[4]*inv, ex[5]*inv, ex[6]*inv, ex[7]*inv };
      float4* gp = (float4*)(gate1 + (size_t)t*8);
      gp[0] = o0; gp[1] = o1;
      top_i[t] = i1 | (i2 << 4);
      float2 g = { 1.f / (1.f + e2), e2 / (1.f + e2) };
      top_g[t] = g;
    }
  }
}

// ---------------- build expert lists: block-aggregated atomics ----------------
__global__ void __launch_bounds__(256) k_build(
    const int* __restrict__ top_i, const float2* __restrict__ top_g,
    int* __restrict__ counts, int* __restrict__ ex_tok, float* __restrict__ ex_gate,
    int2* __restrict__ ppos)
{
  __shared__ int lcnt[8], lbase[8];
  const int tid = threadIdx.x;
  if (tid < 8) lcnt[tid] = 0;
  __syncthreads();
  const int t = blockIdx.x*256 + tid;
  const int ti = top_i[t];
  const int i1 = ti & 15, i2 = ti >> 4;
  const float2 g = top_g[t];
  int p1 = atomicAdd(&lcnt[i1], 1);
  int p2 = atomicAdd(&lcnt[i2], 1);
  __syncthreads();
  if (tid < 8) lbase[tid] = atomicAdd(&counts[tid], lcnt[tid]);
  __syncthreads();
  int s1 = lbase[i1] + p1; ex_tok[i1*NTOK+s1] = t; ex_gate[i1*NTOK+s1] = g.x;
  int s2 = lbase[i2] + p2; ex_tok[i2*NTOK+s2] = t; ex_gate[i2*NTOK+s2] = g.y;
  int2 pp = { i1 | (s1 << 3), i2 | (s2 << 3) };
  ppos[t] = pp;
}

__global__ void k_finalize(const int* __restrict__ counts, int* __restrict__ seg) {
  if (threadIdx.x == 0 && blockIdx.x == 0) {
    int s = 0;
    for (int e = 0; e < 8; ++e) { seg[e] = s; s += (counts[e] + 255) & ~255; }
    seg[8] = s;
  }
}

// W [E][R][C] f32 -> WT [E][C][R] bf16 — vectorized (float4 in, bf16x8 out)
template<int RDIM, int CDIM>
__global__ void __launch_bounds__(256) k_tconv(
    const float* __restrict__ W, __bf16* __restrict__ WT)
{
  const int e  = blockIdx.z;
  const int c0 = blockIdx.x * 64, r0 = blockIdx.y * 64;
  __shared__ float tb[64 * 65];          // [srccol][srcrow], pad 65
  const float* src = W  + (size_t)e * RDIM * CDIM + (size_t)r0 * CDIM + c0;
  __bf16*      dst = WT + (size_t)e * RDIM * CDIM + (size_t)c0 * RDIM + r0;
  const int tx = threadIdx.x & 15, ty = threadIdx.x >> 4;   // 16x16
  #pragma unroll
  for (int i = 0; i < 4; ++i) {
    int r = ty + i*16;
    float4 v = *(const float4*)(src + (size_t)r*CDIM + tx*4);
    tb[(tx*4+0)*65 + r] = v.x; tb[(tx*4+1)*65 + r] = v.y;
    tb[(tx*4+2)*65 + r] = v.z; tb[(tx*4+3)*65 + r] = v.w;
  }
  __syncthreads();
  const int sg = threadIdx.x & 7, dr8 = threadIdx.x >> 3;  // 32 dst rows/iter
  #pragma unroll
  for (int i = 0; i < 2; ++i) {
    int d = dr8 + i*32;
    const float* row = tb + d*65 + sg*8;
    bf16x8 o;
    #pragma unroll
    for (int j = 0; j < 8; ++j) o[j] = (__bf16)row[j];
    *(bf16x8*)(dst + (size_t)d*RDIM + sg*8) = o;
  }
}

// ============ grouped GEMM: 256x256 tile, 8 waves, deep-stagger 4-phase =====
// Per-wave output 128x64 (8Mx4N frags). K-tile=64, dbuf LDS 2x64KB.
// Issue ONE half-tile per phase, TWO tiles ahead (deep prefetch):
//   P1(t)->A1(t+1), P2(t)->A0(t+2), P3(t)->B0(t+2), P4(t)->B1(t+2)
// each targeting the slot freed exactly one barrier earlier. Uniform
// vmcnt(10) per phase close = 5-phase latency cover; tail uses clamped
// re-issues (same src->same dst, benign). Epilogue __syncthreads drains.
template<int KDIM, int KFULL, int NDIM, bool G1>
__global__ void __launch_bounds__(512, 2) k_moe_gemm8(
    const __bf16* __restrict__ Abase, const __bf16* __restrict__ WT,
    const float* __restrict__ bias,
    const int* __restrict__ seg, const int* __restrict__ counts,
    const int* __restrict__ ex_tok,
    int chunk0, __bf16* __restrict__ dstbuf)
{
  constexpr int NT = KDIM / 64;
  const int nx = gridDim.x, ny = gridDim.y, nz = gridDim.z;
  const int total = nx * ny * nz;
  int flat;
  if (G1) flat = blockIdx.x + nx * blockIdx.y;                       // bx fastest
  else    flat = blockIdx.y + ny * (blockIdx.x + nx * blockIdx.z);   // by fastest
  { int q = total >> 3, r = total & 7; int xcd = flat & 7, idx = flat >> 3;
    flat = (xcd < r ? xcd*(q+1) : r*(q+1) + (xcd-r)*q) + idx; }
  int bx, by, bz;
  if (G1) { bx = flat % nx; by = flat / nx; bz = 0; }
  else    { by = flat % ny; int f2 = flat / ny; bx = f2 % nx; bz = f2 / nx; }

  const int segtot = seg[8];
  const int row0 = chunk0 + bx * 256;
  if (row0 >= segtot) return;
  int e = 0;
  #pragma unroll
  for (int qq = 1; qq < 8; ++qq) if (row0 >= seg[qq]) e = qq;
  const int cnt = counts[e], sege = seg[e];
  const int n0 = by * 256;
  const int kbase = bz * KDIM;

  __shared__ __align__(16) char smem[131072];   // 2 x 64KB dbuf / 128KB C-stage

  const int tid = threadIdx.x;
  const int wid = tid >> 6, lane = tid & 63;
  const int wm = wid >> 2, wn = wid & 3;        // 2M x 4N waves
  const int l15 = lane & 15, l4 = lane >> 4;
  const __bf16* Bsrc = WT + (size_t)e * NDIM * KFULL;

  float bv[4];
  if (G1) {
    #pragma unroll
    for (int N = 0; N < 4; ++N)
      bv[N] = bias[(size_t)e*NDIM + n0 + wn*64 + N*16 + l15];
    asm volatile("" :: "v"(bv[0]), "v"(bv[1]), "v"(bv[2]), "v"(bv[3]));
  }

  // staging source pointers: halves h: 0=A-mh0, 1=A-mh1, 2=B-nh0, 3=B-nh1
  const __bf16* sp[4][2];
  #pragma unroll
  for (int j = 0; j < 2; ++j) {
    int g = j*512 + tid;            // 16B-chunk id within a half (1024)
    int sl = g >> 3;                // local slot row 0..127
    int kb = (g & 7) ^ (sl & 7);    // logical k-chunk (inverse-swizzled source)
    #pragma unroll
    for (int mh = 0; mh < 2; ++mh) {
      int wms = (sl >> 6) & 1, rs = sl & 63;
      int R = wms*128 + mh*64 + rs;
      int arow;
      if (G1) { int lr = row0 + R - sege; arow = (lr < cnt) ? ex_tok[e*NTOK + lr] : 0; }
      else    { arow = row0 + R - chunk0; }
      sp[mh][j] = Abase + (size_t)arow * KFULL + kbase + kb*8;
    }
    #pragma unroll
    for (int nh = 0; nh < 2; ++nh) {
      int wns = (sl >> 5) & 3, rs = sl & 31;
      int C = wns*64 + nh*32 + rs;
      sp[2+nh][j] = Bsrc + (size_t)(n0 + C) * KFULL + kbase + kb*8;
    }
  }

  // read offsets
  int xo[2];
  #pragma unroll
  for (int kk = 0; kk < 2; ++kk) xo[kk] = (((kk*4 + l4) ^ (l15 & 7)) * 16);
  int arb[4], brb[2];
  #pragma unroll
  for (int m = 0; m < 4; ++m) arb[m] = (wm*64 + m*16 + l15) * 128;
  #pragma unroll
  for (int n = 0; n < 2; ++n) brb[n] = 32768 + (wn*32 + n*16 + l15) * 128;

  auto ISSUE = [&](int h, int tt) {
    char* b = smem + (tt & 1) * 65536 + h * 16384;
    gload_lds16(sp[h][0] + tt*64, b + tid*16);
    gload_lds16(sp[h][1] + tt*64, b + 8192 + tid*16);
  };

  f32x4 acc[8][4] = {};

  // prologue: tile0 full + tile1 {A0,B0,B1}; A1(1) comes from P1(0)
  ISSUE(0,0); ISSUE(2,0); ISSUE(3,0); ISSUE(1,0);
  ISSUE(0,1); ISSUE(2,1); ISSUE(3,1);
  asm volatile("s_waitcnt vmcnt(10)" ::: "memory");
  __builtin_amdgcn_s_barrier();

  for (int t = 0; t < NT; ++t) {
    const char* cb = smem + (t & 1) * 65536;
    const int tc1 = (t+1 < NT) ? t+1 : NT-1;
    const int tc2 = (t+2 < NT) ? t+2 : NT-1;
    bf16x8 af[4][2], bfr[2][2][2];

    // ---- P1: read A0(8)+B0(4); issue A1(tc1)
    #pragma unroll
    for (int m = 0; m < 4; ++m)
      #pragma unroll
      for (int kk = 0; kk < 2; ++kk)
        af[m][kk] = *(const bf16x8*)(cb + arb[m] + xo[kk]);
    #pragma unroll
    for (int n = 0; n < 2; ++n)
      #pragma unroll
      for (int kk = 0; kk < 2; ++kk)
        bfr[0][n][kk] = *(const bf16x8*)(cb + brb[n] + xo[kk]);
    ISSUE(1, tc1);
    __builtin_amdgcn_s_barrier();
    asm volatile("s_waitcnt lgkmcnt(0)" ::: "memory");
    __builtin_amdgcn_sched_barrier(0);
    __builtin_amdgcn_s_setprio(1);
    #pragma unroll
    for (int m = 0; m < 4; ++m)
      #pragma unroll
      for (int n = 0; n < 2; ++n)
        #pragma unroll
        for (int kk = 0; kk < 2; ++kk)
          acc[m][n] = __builtin_amdgcn_mfma_f32_16x16x32_bf16(af[m][kk], bfr[0][n][kk], acc[m][n], 0, 0, 0);
    __builtin_amdgcn_s_setprio(0);
    asm volatile("s_waitcnt vmcnt(10)" ::: "memory");
    __builtin_amdgcn_s_barrier();

    // ---- P2: read B1(4); issue A0(tc2)
    #pragma unroll
    for (int n = 0; n < 2; ++n)
      #pragma unroll
      for (int kk = 0; kk < 2; ++kk)
        bfr[1][n][kk] = *(const bf16x8*)(cb + 16384 + brb[n] + xo[kk]);
    ISSUE(0, tc2);
    __builtin_amdgcn_s_barrier();
    asm volatile("s_waitcnt lgkmcnt(0)" ::: "memory");
    __builtin_amdgcn_sched_barrier(0);
    __builtin_amdgcn_s_setprio(1);
    #pragma unroll
    for (int m = 0; m < 4; ++m)
      #pragma unroll
      for (int n = 0; n < 2; ++n)
        #pragma unroll
        for (int kk = 0; kk < 2; ++kk)
          acc[m][2+n] = __builtin_amdgcn_mfma_f32_16x16x32_bf16(af[m][kk], bfr[1][n][kk], acc[m][2+n], 0, 0, 0);
    __builtin_amdgcn_s_setprio(0);
    asm volatile("s_waitcnt vmcnt(10)" ::: "memory");
    __builtin_amdgcn_s_barrier();

    // ---- P3: read A1(8); issue B0(tc2)
    #pragma unroll
    for (int m = 0; m < 4; ++m)
      #pragma unroll
      for (int kk = 0; kk < 2; ++kk)
        af[m][kk] = *(const bf16x8*)(cb + 16384 + arb[m] + xo[kk]);
    ISSUE(2, tc2);
    __builtin_amdgcn_s_barrier();
    asm volatile("s_waitcnt lgkmcnt(0)" ::: "memory");
    __builtin_amdgcn_sched_barrier(0);
    __builtin_amdgcn_s_setprio(1);
    #pragma unroll
    for (int m = 0; m < 4; ++m)
      #pragma unroll
      for (int n = 0; n < 2; ++n)
        #pragma unroll
        for (int kk = 0; kk < 2; ++kk)
          acc[4+m][n] = __builtin_amdgcn_mfma_f32_16x16x32_bf16(af[m][kk], bfr[0][n][kk], acc[4+m][n], 0, 0, 0);
    __builtin_amdgcn_s_setprio(0);
    asm volatile("s_waitcnt vmcnt(10)" ::: "memory");
    __builtin_amdgcn_s_barrier();

    // ---- P4: no reads; issue B1(tc2)
    ISSUE(3, tc2);
    __builtin_amdgcn_s_barrier();
    __builtin_amdgcn_s_setprio(1);
    #pragma unroll
    for (int m = 0; m < 4; ++m)
      #pragma unroll
      for (int n = 0; n < 2; ++n)
        #pragma unroll
        for (int kk = 0; kk < 2; ++kk)
          acc[4+m][2+n] = __builtin_amdgcn_mfma_f32_16x16x32_bf16(af[m][kk], bfr[1][n][kk], acc[4+m][2+n], 0, 0, 0);
    __builtin_amdgcn_s_setprio(0);
    asm volatile("s_waitcnt vmcnt(10)" ::: "memory");
    __builtin_amdgcn_s_barrier();
  }

  // ---- epilogue: bias (+GELU if G1), stage 256x256 bf16 C in LDS, store
  __syncthreads();   // drains vmcnt(0) incl. dead tail re-issues
  __bf16* Cl = (__bf16*)smem;   // 128 KB
  #pragma unroll
  for (int M = 0; M < 8; ++M) {
    #pragma unroll
    for (int N = 0; N < 4; ++N) {
      #pragma unroll
      for (int r2 = 0; r2 < 4; ++r2) {
        float v = acc[M][N][r2];
        if (G1) {
          v += bv[N];
          float z = 2.302208f * (v + 0.044715f * v * v * v);  // 2u*log2(e)
          v = v / (1.f + exp2f(-z));
        }
        Cl[(wm*128 + M*16 + l4*4 + r2)*256 + wn*64 + N*16 + l15] = (__bf16)v;
      }
    }
  }
  __syncthreads();
  const int drow0 = G1 ? (row0 - chunk0) : row0;
  __bf16* dst = dstbuf + (G1 ? (size_t)0 : (size_t)bz * MAXPAD * NDIM);
  #pragma unroll
  for (int it = 0; it < 16; ++it) {
    int idx2 = it*512 + tid;
    int rr = idx2 >> 5, c8 = (idx2 & 31) * 8;
    *(bf16x8*)(dst + (size_t)(drow0 + rr)*NDIM + n0 + c8) =
        *(const bf16x8*)(Cl + rr*256 + c8);
  }
}

// -------- combine: out[t] = g1*(P0+P1+b2)[pos1] + g2*(P0+P1+b2)[pos2] --------
__global__ void __launch_bounds__(256) k_combine(
    const __bf16* __restrict__ pbuf, const int2* __restrict__ ppos,
    const float2* __restrict__ top_g, const int* __restrict__ seg,
    const float* __restrict__ b2, float* __restrict__ out)
{
  const int t = blockIdx.x, tid = threadIdx.x;
  const int2 pp = ppos[t];
  const float2 g = top_g[t];
  const int e1 = pp.x & 7, i1 = pp.x >> 3;
  const int e2 = pp.y & 7, i2 = pp.y >> 3;
  const size_t r1 = (size_t)(seg[e1] + i1) * DEMB;
  const size_t r2 = (size_t)(seg[e2] + i2) * DEMB;
  const __bf16* p0 = pbuf;
  const __bf16* p1 = pbuf + (size_t)MAXPAD * DEMB;
  const int c = tid * 4;
  bf16x4v a0 = *(const bf16x4v*)(p0 + r1 + c);
  bf16x4v a1 = *(const bf16x4v*)(p1 + r1 + c);
  bf16x4v c0 = *(const bf16x4v*)(p0 + r2 + c);
  bf16x4v c1 = *(const bf16x4v*)(p1 + r2 + c);
  float4 ba = *(const float4*)(b2 + (size_t)e1*DEMB + c);
  float4 bb = *(const float4*)(b2 + (size_t)e2*DEMB + c);
  float4 o;
  o.x = g.x*((float)a0[0]+(float)a1[0]+ba.x) + g.y*((float)c0[0]+(float)c1[0]+bb.x);
  o.y = g.x*((float)a0[1]+(float)a1[1]+ba.y) + g.y*((float)c0[1]+(float)c1[1]+bb.y);
  o.z = g.x*((float)a0[2]+(float)a1[2]+ba.z) + g.y*((float)c0[2]+(float)c1[2]+bb.z);
  o.w = g.x*((float)a0[3]+(float)a1[3]+ba.w) + g.y*((float)c0[3]+(float)c1[3]+bb.w);
  *(float4*)(out + (size_t)t*DEMB + c) = o;
}

// ---------------- host ----------------
extern "C" void kernel_launch(void* const* d_in, const int* in_sizes, int n_in,
                              void* d_out, int out_size, void* d_ws, size_t ws_size,
                              hipStream_t stream)
{
  const float* x   = (const float*)d_in[0];
  const float* dt  = (const float*)d_in[1];
  const float* dd  = (const float*)d_in[2];
  const float* drg = (const float*)d_in[3];
  const float* de  = (const float*)d_in[4];
  const float* city= (const float*)d_in[5];
  const float* Wg  = (const float*)d_in[6];
  const float* bg  = (const float*)d_in[7];
  const float* W1  = (const float*)d_in[8];
  const float* b1  = (const float*)d_in[9];
  const float* W2  = (const float*)d_in[10];
  const float* b2  = (const float*)d_in[11];
  const int* city_index = (const int*)d_in[12];

  float* out   = (float*)d_out;                    // [NTOK][1024]
  float* gate1 = out + (size_t)NTOK * DEMB;        // [NTOK][8]

  char* p = (char*)d_ws;
  int*    counts  = (int*)p;      p += 256;
  int*    seg     = (int*)p;      p += 256;
  int*    top_i   = (int*)p;      p += (size_t)NTOK*4;
  float2* top_g   = (float2*)p;   p += (size_t)NTOK*8;
  int2*   ppos    = (int2*)p;     p += (size_t)NTOK*8;
  int*    ex_tok  = (int*)p;      p += (size_t)NTOK*NEXP*4;
  float*  ex_gate = (float*)p;    p += (size_t)NTOK*NEXP*4;
  __bf16* xb      = (__bf16*)p;   p += (size_t)NTOK*DEMB*2;
  __bf16* W1T     = (__bf16*)p;   p += (size_t)NEXP*DEMB*HDIM*2;
  __bf16* W2T     = (__bf16*)p;   p += (size_t)NEXP*DEMB*HDIM*2;
  __bf16* pbuf    = (__bf16*)p;   p += (size_t)2*MAXPAD*DEMB*2;   // split-K=2
  __bf16* hbuf    = (__bf16*)p;

  size_t fixed = (size_t)(p - (char*)d_ws);
  int CH = MAXPAD;  // single chunk if workspace allows
  while (CH > 0 && fixed + (size_t)CH * HDIM * 2 > ws_size) CH -= 256;
  if (CH <= 0) return;
  int nch = (MAXPAD + CH - 1) / CH;

  (void)hipMemsetAsync(counts, 0, 64, stream);

  k_tconv<DEMB, HDIM><<<dim3(HDIM/64, DEMB/64, NEXP), 256, 0, stream>>>(W1, W1T);
  k_tconv<HDIM, DEMB><<<dim3(DEMB/64, HDIM/64, NEXP), 256, 0, stream>>>(W2, W2T);

  k_logits<<<NTOK/16, 256, 0, stream>>>(x, dt, dd, drg, de, city, Wg, bg,
                                        city_index, gate1, top_i, top_g, xb);
  k_build<<<NTOK/256, 256, 0, stream>>>(top_i, top_g, counts, ex_tok, ex_gate, ppos);
  k_finalize<<<1, 64, 0, stream>>>(counts, seg);

  for (int c = 0; c < nch; ++c) {
    k_moe_gemm8<1024, 1024, HDIM, true><<<dim3(CH/256, HDIM/256, 1), 512, 0, stream>>>(
        xb, W1T, b1, seg, counts, ex_tok, c*CH, hbuf);
    k_moe_gemm8<2048, 4096, DEMB, false><<<dim3(CH/256, DEMB/256, 2), 512, 0, stream>>>(
        hbuf, W2T, b2, seg, counts, ex_tok, c*CH, pbuf);
  }
  k_combine<<<NTOK, 256, 0, stream>>>(pbuf, ppos, top_g, seg, b2, out);
}